// Round 13
// baseline (227.999 us; speedup 1.0000x reference)
//
#include <hip/hip_runtime.h>

#define SS 2048
#define DD 64
#define QB 64        // q rows per block (2 q-tiles x 32, both owned by every wave)
#define KVB 128      // kv rows per staged tile; wave w owns rows [w*32, w*32+32)
#define NT (SS / KVB)

typedef unsigned short ushort_t;
typedef __attribute__((ext_vector_type(4)))  float f32x4;
typedef __attribute__((ext_vector_type(16))) float f32x16;
typedef __attribute__((ext_vector_type(8)))  short bf16x8;
typedef __attribute__((ext_vector_type(2)))  unsigned int u32x2;

static __device__ __forceinline__ unsigned short f2bf(float f) {
    unsigned u = __builtin_bit_cast(unsigned, f);
    u += 0x7FFFu + ((u >> 16) & 1u);
    return (unsigned short)(u >> 16);
}

static __device__ __forceinline__ f32x16 zero16() {
    f32x16 z;
#pragma unroll
    for (int i = 0; i < 16; ++i) z[i] = 0.f;
    return z;
}

union PFrag { bf16x8 v; unsigned w[4]; };

#define GLL16(src, dst) \
    __builtin_amdgcn_global_load_lds((const __attribute__((address_space(1))) void*)(src), \
                                     (__attribute__((address_space(3))) void*)(dst), 16, 0, 0)

// ---------------- merged prologue: K fp32->bf16 (blocks 0..2047), V transpose (2048..3071) ----------------
__global__ void prep(const float* __restrict__ K, const float* __restrict__ V,
                     ushort_t* __restrict__ Kbf, ushort_t* __restrict__ Vt)
{
    const int tid = threadIdx.x;
    if (blockIdx.x < 2048) {
        int i = blockIdx.x * 256 + tid;
        f32x4 a = ((const f32x4*)K)[2 * i];
        f32x4 b = ((const f32x4*)K)[2 * i + 1];
        bf16x8 o;
#pragma unroll
        for (int j = 0; j < 4; ++j) o[j] = (short)f2bf(a[j]);
#pragma unroll
        for (int j = 0; j < 4; ++j) o[4 + j] = (short)f2bf(b[j]);
        ((bf16x8*)Kbf)[i] = o;
        return;
    }
    __shared__ float tile[64][65];
    const int bid2 = blockIdx.x - 2048;
    const int hh = bid2 >> 5;
    const int kt = bid2 & 31;
#pragma unroll
    for (int it = 0; it < 4; ++it) {
        int m = it * 256 + tid;
        int r = m >> 4, c4 = m & 15;
        f32x4 v = *(const f32x4*)(V + ((size_t)(hh * SS + kt * 64 + r)) * DD + c4 * 4);
#pragma unroll
        for (int j = 0; j < 4; ++j) tile[r][c4 * 4 + j] = v[j];
    }
    __syncthreads();
#pragma unroll
    for (int it = 0; it < 2; ++it) {
        int m = it * 256 + tid;
        int d = m >> 3, c8 = m & 7;
        bf16x8 o;
#pragma unroll
        for (int j = 0; j < 8; ++j) o[j] = (short)f2bf(tile[c8 * 8 + j][d]);
        *(bf16x8*)(Vt + ((size_t)hh * DD + d) * SS + kt * 64 + c8 * 8) = o;
    }
}

// ---------------- main: fragment-sharing (each ds_read feeds 2 MFMAs) ----------------
__global__ __launch_bounds__(256, 2)
void attn_main10(const float* __restrict__ gQ, const ushort_t* __restrict__ Kbf,
                 const ushort_t* __restrict__ Vtbf, float* __restrict__ gO,
                 float* __restrict__ gP)
{
    __shared__ float lsm[4][2][32];                            // [wave][q-tile][q]
    __shared__ __attribute__((aligned(16))) char shraw[65536]; // [2 buf][K 16KB | V 16KB]; osm union
    ushort_t* stage = (ushort_t*)shraw;
    float*    osm   = (float*)shraw;                           // [4][64][33] after main loop

    const int tid  = threadIdx.x;
    const int lane = tid & 63;
    const int wave = tid >> 6;
    const int lo5  = lane & 31;
    const int hi   = lane >> 5;

    const int bid  = blockIdx.x;
    const int wg   = (bid & 7) * 128 + (bid >> 3);  // XCD-contiguous (4 heads/XCD)
    const int head = wg >> 5;
    const int q0b  = (wg & 31) * QB;

    const float*    Qh = gQ   + (size_t)head * SS * DD;
    const ushort_t* Kh = Kbf  + (size_t)head * SS * DD;
    const ushort_t* Vh = Vtbf + (size_t)head * DD * SS;   // [d][kv]
    float* Oh = gO + (size_t)head * SS * DD;
    float* Ph = gP + (size_t)head * SS * SS;

    const float SCALE = 0.125f * 1.44269504088896340736f; // (1/sqrt(64)) * log2(e)

    // ---- Q B-fragments for BOTH q-tiles (scale+log2e folded) ----
    bf16x8 qf2[2][4];
#pragma unroll
    for (int p = 0; p < 2; ++p)
#pragma unroll
        for (int ks = 0; ks < 4; ++ks) {
            const float* qp = Qh + (size_t)(q0b + p * 32 + lo5) * DD + ks * 16 + hi * 8;
            f32x4 a = *(const f32x4*)(qp);
            f32x4 b = *(const f32x4*)(qp + 4);
            bf16x8 o;
#pragma unroll
            for (int j = 0; j < 4; ++j) o[j] = (short)f2bf(a[j] * SCALE);
#pragma unroll
            for (int j = 0; j < 4; ++j) o[4 + j] = (short)f2bf(b[j] * SCALE);
            qf2[p][ks] = o;
        }

    // ---- staging addresses (R12-proven: source pre-swizzled, LDS dest linear) ----
    const int lgrp = lane >> 3;
    const int kchk = (lane & 7) ^ lgrp;
    const ushort_t* srcK[4];
    const ushort_t* srcV[4];
#pragma unroll
    for (int j = 0; j < 4; ++j) {
        int W = wave * 4 + j;
        srcK[j] = Kh + (size_t)(W * 8 + lgrp) * DD + kchk * 8;
        int d = W * 4 + (lane >> 4);
        int vchk = (lane & 15) ^ (d & 7);
        srcV[j] = Vh + (size_t)d * SS + vchk * 8;
    }
    const int kvl = wave * 32 + lo5;       // this wave's K row within the 128-tile

    // ================= PASS A: denominators (max-free), kf shared across 2 q-tiles =================
#pragma unroll
    for (int j = 0; j < 4; ++j) GLL16(srcK[j], stage + (wave * 4 + j) * 512);
    __syncthreads();

    float ls00 = 0.f, ls01 = 0.f, ls10 = 0.f, ls11 = 0.f;
    for (int t = 0; t < NT; ++t) {
        const int buf = t & 1;
        if (t + 1 < NT) {
#pragma unroll
            for (int j = 0; j < 4; ++j)
                GLL16(srcK[j] + (size_t)(t + 1) * KVB * DD,
                      stage + (buf ^ 1) * 16384 + (wave * 4 + j) * 512);
        }
        const ushort_t* Ksb = stage + buf * 16384;
        bf16x8 kf[4];
#pragma unroll
        for (int ks = 0; ks < 4; ++ks)
            kf[ks] = *(const bf16x8*)(Ksb + kvl * 64 + ((((ks * 2) + hi) ^ (kvl & 7)) << 3));
        f32x16 a0 = zero16(), a1 = zero16();
#pragma unroll
        for (int ks = 0; ks < 4; ++ks) {
            a0 = __builtin_amdgcn_mfma_f32_32x32x16_bf16(kf[ks], qf2[0][ks], a0, 0, 0, 0);
            a1 = __builtin_amdgcn_mfma_f32_32x32x16_bf16(kf[ks], qf2[1][ks], a1, 0, 0, 0);
        }
#pragma unroll
        for (int r = 0; r < 16; r += 2) {
            ls00 += __builtin_exp2f(a0[r]);
            ls01 += __builtin_exp2f(a0[r + 1]);
            ls10 += __builtin_exp2f(a1[r]);
            ls11 += __builtin_exp2f(a1[r + 1]);
        }
        __syncthreads();
    }
    {
        float l0 = ls00 + ls01, l1 = ls10 + ls11;
        l0 += __shfl_xor(l0, 32);
        l1 += __shfl_xor(l1, 32);
        lsm[wave][0][lo5] = l0;
        lsm[wave][1][lo5] = l1;
    }
    __syncthreads();
    const float rinv0 = 1.0f / (lsm[0][0][lo5] + lsm[1][0][lo5] + lsm[2][0][lo5] + lsm[3][0][lo5]);
    const float rinv1 = 1.0f / (lsm[0][1][lo5] + lsm[1][1][lo5] + lsm[2][1][lo5] + lsm[3][1][lo5]);

    // ================= PASS B: scores, P write, PV; kf+vf shared across 2 q-tiles =================
    f32x16 o00 = zero16(), o01 = zero16(), o10 = zero16(), o11 = zero16(); // [p][dt]

#pragma unroll
    for (int j = 0; j < 4; ++j) {
        GLL16(srcK[j], stage + (wave * 4 + j) * 512);
        GLL16(srcV[j], stage + 8192 + (wave * 4 + j) * 512);
    }
    __syncthreads();

    for (int t = 0; t < NT; ++t) {
        const int buf = t & 1;
        if (t + 1 < NT) {
#pragma unroll
            for (int j = 0; j < 4; ++j) {
                GLL16(srcK[j] + (size_t)(t + 1) * KVB * DD,
                      stage + (buf ^ 1) * 16384 + (wave * 4 + j) * 512);
                GLL16(srcV[j] + (size_t)(t + 1) * KVB,
                      stage + (buf ^ 1) * 16384 + 8192 + (wave * 4 + j) * 512);
            }
        }
        const ushort_t* Ksb = stage + buf * 16384;
        const ushort_t* Vtb = Ksb + 8192;       // [64 d][128 kv], 16 chunks/row, low3^(d&7)

        // K fragments: 4 reads, feed 8 MFMAs
        bf16x8 kf[4];
#pragma unroll
        for (int ks = 0; ks < 4; ++ks)
            kf[ks] = *(const bf16x8*)(Ksb + kvl * 64 + ((((ks * 2) + hi) ^ (kvl & 7)) << 3));
        f32x16 a0 = zero16(), a1 = zero16();
#pragma unroll
        for (int ks = 0; ks < 4; ++ks) {
            a0 = __builtin_amdgcn_mfma_f32_32x32x16_bf16(kf[ks], qf2[0][ks], a0, 0, 0, 0);
            a1 = __builtin_amdgcn_mfma_f32_32x32x16_bf16(kf[ks], qf2[1][ks], a1, 0, 0, 0);
        }

        // V fragments: 4 reads (dt x ksub), shared by both q-tiles
        bf16x8 vf[2][2];
#pragma unroll
        for (int dt = 0; dt < 2; ++dt) {
            int drow = dt * 32 + lo5;
#pragma unroll
            for (int ksub = 0; ksub < 2; ++ksub) {
                int m = wave * 4 + ksub * 2 + hi;                 // logical 8-kv chunk
                int c = (m & 8) | ((m & 7) ^ (drow & 7));         // stored position
                vf[dt][ksub] = *(const bf16x8*)(Vtb + drow * 128 + (c << 3));
            }
        }

#pragma unroll
        for (int p = 0; p < 2; ++p) {
            const f32x16& acc = p ? a1 : a0;
            const float rinv = p ? rinv1 : rinv0;
            float pr[16];
#pragma unroll
            for (int r = 0; r < 16; ++r) pr[r] = __builtin_exp2f(acc[r]);

            // normalized P store: row q0b+p*32+lo5, kv = t*128 + wave*32 + 8g+4hi+j
            float* prow = Ph + (size_t)(q0b + p * 32 + lo5) * SS + t * KVB + wave * 32;
#pragma unroll
            for (int g = 0; g < 4; ++g) {
                f32x4 st = { pr[4*g+0] * rinv, pr[4*g+1] * rinv, pr[4*g+2] * rinv, pr[4*g+3] * rinv };
                *(f32x4*)(prow + g * 8 + hi * 4) = st;
            }

            // pack + half-wave exchange -> P^T B-frags (R2-proven)
            unsigned u[8];
#pragma unroll
            for (int j = 0; j < 8; ++j)
                u[j] = (unsigned)f2bf(pr[2*j]) | ((unsigned)f2bf(pr[2*j+1]) << 16);
            unsigned s0 = __shfl_xor(u[0], 32), s1 = __shfl_xor(u[1], 32);
            unsigned s2 = __shfl_xor(u[2], 32), s3 = __shfl_xor(u[3], 32);
            unsigned s4 = __shfl_xor(u[4], 32), s5 = __shfl_xor(u[5], 32);
            unsigned s6 = __shfl_xor(u[6], 32), s7 = __shfl_xor(u[7], 32);
            PFrag pf0, pf1;
            pf0.w[0] = hi ? s2 : u[0];  pf0.w[1] = hi ? s3 : u[1];
            pf0.w[2] = hi ? u[2] : s0;  pf0.w[3] = hi ? u[3] : s1;
            pf1.w[0] = hi ? s6 : u[4];  pf1.w[1] = hi ? s7 : u[5];
            pf1.w[2] = hi ? u[6] : s4;  pf1.w[3] = hi ? u[7] : s5;

            // PV: O^T_p[64d][32q] += V^T * P^T_p
            f32x16& od0 = p ? o10 : o00;
            f32x16& od1 = p ? o11 : o01;
            od0 = __builtin_amdgcn_mfma_f32_32x32x16_bf16(vf[0][0], pf0.v, od0, 0, 0, 0);
            od0 = __builtin_amdgcn_mfma_f32_32x32x16_bf16(vf[0][1], pf1.v, od0, 0, 0, 0);
            od1 = __builtin_amdgcn_mfma_f32_32x32x16_bf16(vf[1][0], pf0.v, od1, 0, 0, 0);
            od1 = __builtin_amdgcn_mfma_f32_32x32x16_bf16(vf[1][1], pf1.v, od1, 0, 0, 0);
        }
        __syncthreads();
    }

    // ================= epilogue: two rounds of 4-way O reduce (R4-proven pattern) =================
#pragma unroll
    for (int p = 0; p < 2; ++p) {
#pragma unroll
        for (int dt = 0; dt < 2; ++dt) {
            const f32x16& od = p ? (dt ? o11 : o10) : (dt ? o01 : o00);
#pragma unroll
            for (int g = 0; g < 4; ++g) {
#pragma unroll
                for (int j = 0; j < 4; ++j) {
                    int d = dt * 32 + g * 8 + hi * 4 + j;
                    osm[(wave * 64 + d) * 33 + lo5] = od[4 * g + j];
                }
            }
        }
        __syncthreads();
        {
            const int q  = tid >> 3;
            const int d0 = (tid & 7) * 8;
            const float rq = 1.0f / (lsm[0][p][q] + lsm[1][p][q] + lsm[2][p][q] + lsm[3][p][q]);
            float out[8];
#pragma unroll
            for (int i = 0; i < 8; ++i) {
                int d = d0 + i;
                out[i] = (osm[(0 * 64 + d) * 33 + q] + osm[(1 * 64 + d) * 33 + q] +
                          osm[(2 * 64 + d) * 33 + q] + osm[(3 * 64 + d) * 33 + q]) * rq;
            }
            float* op = Oh + (size_t)(q0b + p * 32 + q) * DD + d0;
            f32x4 x = { out[0], out[1], out[2], out[3] };
            f32x4 y = { out[4], out[5], out[6], out[7] };
            *(f32x4*)(op)     = x;
            *(f32x4*)(op + 4) = y;
        }
        __syncthreads();
    }
}

// ================= fallback (no-ws path) =================
__global__ __launch_bounds__(256, 2)
void attn_fused(const float* __restrict__ gQ, const float* __restrict__ gK,
                const float* __restrict__ gV, float* __restrict__ gO,
                float* __restrict__ gP)
{
    __shared__ unsigned short Qs[128 * DD];
    __shared__ unsigned short Ks[64 * DD];
    __shared__ unsigned short Vt[DD * 64];

    const int tid  = threadIdx.x;
    const int lane = tid & 63;
    const int wave = tid >> 6;
    const int lo5  = lane & 31;
    const int hi   = lane >> 5;

    const int head = blockIdx.x >> 4;
    const int q0b  = (blockIdx.x & 15) * 128;

    const float* Qh = gQ + (size_t)head * SS * DD;
    const float* Kh = gK + (size_t)head * SS * DD;
    const float* Vh = gV + (size_t)head * SS * DD;
    float* Oh = gO + (size_t)head * SS * DD;
    float* Ph = gP + (size_t)head * SS * SS;

    const float SCALE = 0.125f * 1.44269504088896340736f;

#pragma unroll
    for (int it = 0; it < 8; ++it) {
        int m = it * 256 + tid;
        int q = m >> 4, d4 = m & 15;
        f32x4 v = *(const f32x4*)(Qh + (size_t)(q0b + q) * DD + d4 * 4);
        unsigned a = (unsigned)f2bf(v.x * SCALE) | ((unsigned)f2bf(v.y * SCALE) << 16);
        unsigned b = (unsigned)f2bf(v.z * SCALE) | ((unsigned)f2bf(v.w * SCALE) << 16);
        u32x2 w; w.x = a; w.y = b;
        *(u32x2*)(Qs + q * 64 + d4 * 4) = w;
    }
    __syncthreads();

    const int qrow = wave * 32 + lo5;
    bf16x8 qf[4];
#pragma unroll
    for (int ks = 0; ks < 4; ++ks)
        qf[ks] = *(const bf16x8*)(Qs + qrow * 64 + ks * 16 + hi * 8);

    auto stageK = [&](int kv0) {
#pragma unroll
        for (int it = 0; it < 4; ++it) {
            int m = it * 256 + tid;
            int kv = m >> 4, d4 = m & 15;
            f32x4 v = *(const f32x4*)(Kh + (size_t)(kv0 + kv) * DD + d4 * 4);
            unsigned a = (unsigned)f2bf(v.x) | ((unsigned)f2bf(v.y) << 16);
            unsigned b = (unsigned)f2bf(v.z) | ((unsigned)f2bf(v.w) << 16);
            int c16 = (d4 >> 1) ^ (kv & 7);
            u32x2 w; w.x = a; w.y = b;
            *(u32x2*)(Ks + kv * 64 + c16 * 8 + (d4 & 1) * 4) = w;
        }
    };
    auto stageV = [&](int kv0) {
#pragma unroll
        for (int it = 0; it < 2; ++it) {
            int m = it * 256 + tid;
            int kv2 = m >> 4, d4 = m & 15;
            const float* p0 = Vh + (size_t)(kv0 + kv2 * 2) * DD + d4 * 4;
            f32x4 v0 = *(const f32x4*)(p0);
            f32x4 v1 = *(const f32x4*)(p0 + DD);
#pragma unroll
            for (int c = 0; c < 4; ++c) {
                int d = d4 * 4 + c;
                unsigned u = (unsigned)f2bf(v0[c]) | ((unsigned)f2bf(v1[c]) << 16);
                int c16 = (kv2 >> 2) ^ (d & 7);
                *(unsigned*)(Vt + d * 64 + c16 * 8 + (kv2 & 3) * 2) = u;
            }
        }
    };

    float m_run = -1e30f, l_run = 0.f;
    for (int kv0 = 0; kv0 < SS; kv0 += 64) {
        __syncthreads();
        stageK(kv0);
        __syncthreads();
#pragma unroll
        for (int sub = 0; sub < 2; ++sub) {
            f32x16 acc = zero16();
            int kvl = sub * 32 + lo5;
#pragma unroll
            for (int ks = 0; ks < 4; ++ks) {
                bf16x8 kf = *(const bf16x8*)(Ks + kvl * 64 + ((((ks * 2) + hi) ^ (kvl & 7)) << 3));
                acc = __builtin_amdgcn_mfma_f32_32x32x16_bf16(kf, qf[ks], acc, 0, 0, 0);
            }
            float tm = acc[0];
#pragma unroll
            for (int r = 1; r < 16; ++r) tm = fmaxf(tm, acc[r]);
            float mn = fmaxf(m_run, tm);
            float sum = 0.f;
#pragma unroll
            for (int r = 0; r < 16; ++r) sum += __builtin_exp2f(acc[r] - mn);
            l_run = l_run * __builtin_exp2f(m_run - mn) + sum;
            m_run = mn;
        }
    }
    {
        float mo = __shfl_xor(m_run, 32);
        float mf = fmaxf(m_run, mo);
        float la = l_run * __builtin_exp2f(m_run - mf);
        float lb = __shfl_xor(la, 32);
        l_run = la + lb;
        m_run = mf;
    }
    const float rinv = 1.0f / l_run;

    f32x16 o0 = zero16(), o1 = zero16();
    const int qg = q0b + wave * 32 + lo5;
    float* prow_base = Ph + (size_t)qg * SS;

    for (int kv0 = 0; kv0 < SS; kv0 += 64) {
        __syncthreads();
        stageK(kv0);
        stageV(kv0);
        __syncthreads();
#pragma unroll
        for (int sub = 0; sub < 2; ++sub) {
            f32x16 acc = zero16();
            int kvl = sub * 32 + lo5;
#pragma unroll
            for (int ks = 0; ks < 4; ++ks) {
                bf16x8 kf = *(const bf16x8*)(Ks + kvl * 64 + ((((ks * 2) + hi) ^ (kvl & 7)) << 3));
                acc = __builtin_amdgcn_mfma_f32_32x32x16_bf16(kf, qf[ks], acc, 0, 0, 0);
            }
            float pr[16];
#pragma unroll
            for (int r = 0; r < 16; ++r) pr[r] = __builtin_exp2f(acc[r] - m_run);

            float* prow = prow_base + kv0 + sub * 32;
#pragma unroll
            for (int g = 0; g < 4; ++g) {
                f32x4 st = { pr[4*g+0] * rinv, pr[4*g+1] * rinv, pr[4*g+2] * rinv, pr[4*g+3] * rinv };
                *(f32x4*)(prow + g * 8 + hi * 4) = st;
            }

            unsigned u[8];
#pragma unroll
            for (int j = 0; j < 8; ++j)
                u[j] = (unsigned)f2bf(pr[2*j]) | ((unsigned)f2bf(pr[2*j+1]) << 16);

            unsigned s0 = __shfl_xor(u[0], 32), s1 = __shfl_xor(u[1], 32);
            unsigned s2 = __shfl_xor(u[2], 32), s3 = __shfl_xor(u[3], 32);
            unsigned s4 = __shfl_xor(u[4], 32), s5 = __shfl_xor(u[5], 32);
            unsigned s6 = __shfl_xor(u[6], 32), s7 = __shfl_xor(u[7], 32);
            PFrag pf0, pf1;
            pf0.w[0] = hi ? s2 : u[0];  pf0.w[1] = hi ? s3 : u[1];
            pf0.w[2] = hi ? u[2] : s0;  pf0.w[3] = hi ? u[3] : s1;
            pf1.w[0] = hi ? s6 : u[4];  pf1.w[1] = hi ? s7 : u[5];
            pf1.w[2] = hi ? u[6] : s4;  pf1.w[3] = hi ? u[7] : s5;

#pragma unroll
            for (int dt = 0; dt < 2; ++dt) {
                int drow = dt * 32 + lo5;
                int c0 = ((sub * 4) + 0 + hi) ^ (drow & 7);
                int c1 = ((sub * 4) + 2 + hi) ^ (drow & 7);
                bf16x8 vf0 = *(const bf16x8*)(Vt + drow * 64 + (c0 << 3));
                bf16x8 vf1 = *(const bf16x8*)(Vt + drow * 64 + (c1 << 3));
                f32x16& od = dt ? o1 : o0;
                od = __builtin_amdgcn_mfma_f32_32x32x16_bf16(vf0, pf0.v, od, 0, 0, 0);
                od = __builtin_amdgcn_mfma_f32_32x32x16_bf16(vf1, pf1.v, od, 0, 0, 0);
            }
        }
    }

    float* orow = Oh + (size_t)qg * DD;
#pragma unroll
    for (int dt = 0; dt < 2; ++dt) {
        const f32x16& od = dt ? o1 : o0;
#pragma unroll
        for (int g = 0; g < 4; ++g) {
            f32x4 st = { od[4*g+0] * rinv, od[4*g+1] * rinv, od[4*g+2] * rinv, od[4*g+3] * rinv };
            *(f32x4*)(orow + dt * 32 + g * 8 + hi * 4) = st;
        }
    }
}

extern "C" void kernel_launch(void* const* d_in, const int* in_sizes, int n_in,
                              void* d_out, int out_size, void* d_ws, size_t ws_size,
                              hipStream_t stream) {
    const float* Q = (const float*)d_in[0];
    const float* K = (const float*)d_in[1];
    const float* V = (const float*)d_in[2];
    float* O = (float*)d_out;
    float* P = O + (size_t)2 * 16 * SS * DD;

    const size_t HD = (size_t)32 * SS * DD;           // elems per tensor
    const size_t need = 2 * HD * sizeof(ushort_t);    // K bf16 + V^T bf16 ≈ 16.8 MB

    if (ws_size >= need) {
        ushort_t* Kbf  = (ushort_t*)d_ws;
        ushort_t* Vtbf = Kbf + HD;
        hipLaunchKernelGGL(prep, dim3(3072), dim3(256), 0, stream, K, V, Kbf, Vtbf);
        hipLaunchKernelGGL(attn_main10, dim3(1024), dim3(256), 0, stream, Q, Kbf, Vtbf, O, P);
    } else {
        hipLaunchKernelGGL(attn_fused, dim3(512), dim3(256), 0, stream, Q, K, V, O, P);
    }
}